// Round 3
// baseline (140.429 us; speedup 1.0000x reference)
//
#include <hip/hip_runtime.h>
#include <hip/hip_bf16.h>

typedef short s8v __attribute__((ext_vector_type(8)));      // 8 bf16 (4 VGPRs) MFMA A/B frag
typedef float f4v __attribute__((ext_vector_type(4)));      // MFMA C/D frag
typedef unsigned u4v __attribute__((ext_vector_type(4)));   // 4 packed bf16-pairs

__device__ __forceinline__ unsigned short f2bf(float x) {  // RTNE fp32->bf16 (prep only)
  unsigned u = __builtin_bit_cast(unsigned, x);
  u += 0x7fffu + ((u >> 16) & 1u);
  return (unsigned short)(u >> 16);
}
// pack 2 fp32 -> packed bf16 pair {lo=a, hi=b}
#if __has_builtin(__builtin_amdgcn_cvt_pk_bf16_f32)
__device__ __forceinline__ unsigned pk2(float a, float b) {
  return __builtin_bit_cast(unsigned, __builtin_amdgcn_cvt_pk_bf16_f32(a, b));
}
#else
__device__ __forceinline__ unsigned pk2(float a, float b) {  // 3 VALU ops, round-away
  unsigned ua = __builtin_bit_cast(unsigned, a) + 0x8000u;
  unsigned ub = __builtin_bit_cast(unsigned, b) + 0x8000u;
  return __builtin_amdgcn_perm(ub, ua, 0x07060302u);  // {ub.hi16, ua.hi16}
}
#endif

// ---------------- prep: W1f/W2f fragment packs + latent->bf16 table ----------------
// ws layout (unsigned short): [0,8192) W1f, [8192,24576) W2f, [24576,+524288) latbf.
// (unchanged from R16 baseline)
__global__ void prep_kernel(const float* __restrict__ W1, const float* __restrict__ b1,
                            const float* __restrict__ W2, const float* __restrict__ latent,
                            unsigned short* __restrict__ wsW) {
  int e = blockIdx.x * 256 + threadIdx.x;   // 608*256 = 155648 = 24576 + 131072
  if (e < 8192) {
    int frag = e >> 9, rem = e & 511, lane = rem >> 3, j = rem & 7;
    int h = frag >> 1, ks = frag & 1;
    int q4 = lane >> 4, l15 = lane & 15;
    int k = ks * 32 + q4 * 8 + j;
    int n = h * 16 + l15;
    float v;
    if (k < 13) v = W1[k * 128 + n];
    else if (k == 13) v = b1[n];
    else if (k < 16) v = 0.0f;
    else v = W1[(k - 3) * 128 + n];
    wsW[e] = f2bf(v);
  } else if (e < 24576) {
    int e2 = e - 8192;
    int frag = e2 >> 9, rem = e2 & 511, lane = rem >> 3, j = rem & 7;
    int h2 = frag >> 2, ks = frag & 3;
    int q4 = lane >> 4, l15 = lane & 15;
    int kd = (j < 4) ? (32 * ks + 4 * q4 + j) : (32 * ks + 16 + 4 * q4 + (j - 4));
    int n = h2 * 16 + l15;
    wsW[e] = f2bf(W2[kd * 128 + n]);
  } else {
    int i = e - 24576;                      // 4 floats -> 2 dwords, coalesced
    float4 v = ((const float4*)latent)[i];
    uint2 o;
    o.x = pk2(v.x, v.y);
    o.y = pk2(v.z, v.w);
    ((uint2*)(wsW + 24576))[i] = o;
  }
}

// ---------------- main fused kernel (R18: 1-wave blocks, zero barriers) ----------------
// THEORY (R18): R16's 44us main vs ~6us throughput floor = unhidden latency +
// 4-wave barrier convoy (last wave's phase-0 gates all; vmcnt0+lgkm0 drain) at
// 2 waves/SIMD. Fix: fully decouple waves. 64-thread blocks (1 wave, 64 rows),
// grid 8192, NO __syncthreads, NO W2s/BW LDS staging (GEMM2 weights read direct
// from global -- 48KB L1/L2-hot broadcast, each fragment used once so no reg
// bloat), NO forced W1r preload (each W1 frag used once; let the scheduler
// pipeline). PE stays in 2KB LDS (same-wave write->read, lgkmcnt-ordered).
// NO __launch_bounds__ (avoids gfx950 50/50 arch/acc split seen in R17).
// Expect VGPR ~150-170 -> 10-13 independent waves/CU (vs 8 coupled).
__global__ void lisagon_main(
    const float* __restrict__ coord, const unsigned short* __restrict__ latbf,
    const unsigned short* __restrict__ W1f, const unsigned short* __restrict__ W2f,
    const float* __restrict__ b2, const float* __restrict__ W3,
    const float* __restrict__ b3, float* __restrict__ out) {
  __shared__ __align__(16) unsigned PE[2][64][4];          // 2 KB: 2 planes x 64 rows

  const int t = threadIdx.x;                // 0..63, == lane
  const int lane = t;
  const int l15 = lane & 15, q4 = lane >> 4;
  // XCD-aware swizzle (bijective on [0,8192)): phys blocks with i%8 in {2j,2j+1}
  // (one XCD pair under round-robin) land in batch j = bid>>11. Each XCD serves
  // ONE batch (~260 KB L2 working set). Speed-only heuristic (G16-safe).
  const int bid = ((blockIdx.x & 7) >> 1) * 2048 + ((blockIdx.x >> 3) << 1) + (blockIdx.x & 1);

  // ---- phase 0: idx + area + PE for row t (all 64 lanes dense) ----
  int idx;
  float area;
  {
    const int Rg = bid * 64 + t;
    const int gq = Rg >> 1, p = Rg & 1;       // p=0 -> vx=-2 pass, p=1 -> vx=0 pass
    const float co = coord[gq];
    float c = (co + (p ? 0.0f : -0.000244140625f)) + 1e-6f;  // vx*rx exact
    c = fminf(fmaxf(c, -1.0f + 1e-6f), 1.0f - 1e-6f);
    double u = ((double)c * 8192.0 + 8191.0) * 0.5;          // exact searchsorted
    idx = (int)ceil(u);
    idx = min(max(idx, 0), 8191);
    float qc = ((float)(2 * idx + 1) - 8192.0f) * (1.0f / 8192.0f);  // exact grid[idx]
    float rel = (co - qc) * 8192.0f;
    area = fabsf(rel) + 1e-9f;
    float v[16];
    v[0] = rel;
    float f = rel;
#pragma unroll
    for (int i = 0; i < 6; i++) {
      v[1 + 2 * i] = __sinf(f);
      v[2 + 2 * i] = __cosf(f);
      f = f + f;                 // exact power-of-2 freqs
    }
    v[13] = 1.0f;                // bias-fold slot (W1f input dim 13 = b1)
    v[14] = 0.0f; v[15] = 0.0f;
    uint4 q0, q1;
    q0.x = pk2(v[0], v[1]);   q0.y = pk2(v[2], v[3]);
    q0.z = pk2(v[4], v[5]);   q0.w = pk2(v[6], v[7]);
    q1.x = pk2(v[8], v[9]);   q1.y = pk2(v[10], v[11]);
    q1.z = pk2(v[12], v[13]); q1.w = pk2(v[14], v[15]);
    ((uint4*)PE[0])[t] = q0;   // plane 0: values 0..7 of row t
    ((uint4*)PE[1])[t] = q1;   // plane 1: values 8..15
  }

  // ---- per-lane direct B-fragment assembly (intra-wave only; NO barrier) ----
  // chunk map: ks0: q4<2 -> PE plane q4; q4>=2 -> prev, chunk q4&1. ks1: q4<2 ->
  // self, chunk q4&1; q4>=2 -> next, chunk q4&1.
  const size_t bbase = (size_t)(bid >> 11) * (8192 * 16);  // batch, WG-uniform
  const uint4* latv4 = (const uint4*)(latbf + bbase);   // row r chunk c = latv4[r*2+c]
  s8v Bf[2][4];
#pragma unroll
  for (int rt = 0; rt < 4; rt++) {
    int srcl = rt * 16 + l15;                // source lane (same wave) for this row
    int sidx = __shfl(idx, srcl, 64);
    int rp = max(sidx - 1, 0), rn = min(sidx + 1, 8191);
    int c = q4 & 1;
    uint4 g0 = latv4[rp * 2 + c];                        // ks0 chunk (q4>=2; dummy else)
    uint4 g1 = latv4[(q4 < 2 ? sidx : rn) * 2 + c];      // ks1 chunk
    uint4 pe = ((const uint4*)PE[c])[srcl];              // PE chunk (q4<2; dummy else)
    uint4 b0;
    b0.x = q4 < 2 ? pe.x : g0.x;  b0.y = q4 < 2 ? pe.y : g0.y;
    b0.z = q4 < 2 ? pe.z : g0.z;  b0.w = q4 < 2 ? pe.w : g0.w;
    Bf[0][rt] = __builtin_bit_cast(s8v, b0);
    Bf[1][rt] = __builtin_bit_cast(s8v, g1);
  }

  // ---- GEMM1' (h-outer): W1 frags loaded direct (each used once); relu+pack
  // DIRECTLY into bbv lanes. bbv[rt][ks] is GEMM2's B-fragment for K-chunk ks
  // (K-permuted to match W2f prep layout). ----
  const s8v* W1fv = (const s8v*)W1f;
  u4v bbv[4][4];
#pragma unroll
  for (int h = 0; h < 8; h++) {
    f4v a[4];
#pragma unroll
    for (int rt = 0; rt < 4; rt++) a[rt] = (f4v){0.f, 0.f, 0.f, 0.f};
#pragma unroll
    for (int ks = 0; ks < 2; ks++) {
      s8v w1 = W1fv[(h * 2 + ks) * 64 + lane];   // global, L1-hot broadcast
#pragma unroll
      for (int rt = 0; rt < 4; rt++)
        a[rt] = __builtin_amdgcn_mfma_f32_16x16x32_bf16(w1, Bf[ks][rt], a[rt], 0, 0, 0);
    }
#pragma unroll
    for (int rt = 0; rt < 4; rt++) {
      bbv[rt][h >> 1][2 * (h & 1)]     = pk2(fmaxf(a[rt][0], 0.f), fmaxf(a[rt][1], 0.f));
      bbv[rt][h >> 1][2 * (h & 1) + 1] = pk2(fmaxf(a[rt][2], 0.f), fmaxf(a[rt][3], 0.f));
    }
  }

  // ---- GEMM2' (h2-outer, weights direct from global): b2 as acc-init ----
  const s8v* W2fv = (const s8v*)W2f;
  float s[4] = {0.f, 0.f, 0.f, 0.f};
#pragma unroll
  for (int h2 = 0; h2 < 8; h2++) {
    f4v a2[4];
    f4v b2v = ((const f4v*)b2)[h2 * 4 + q4];   // global, L1-hot; elem i -> 16h2+4q4+i
#pragma unroll
    for (int rt = 0; rt < 4; rt++) a2[rt] = b2v;
#pragma unroll
    for (int ks = 0; ks < 4; ks++) {
      s8v Af = W2fv[(h2 * 4 + ks) * 64 + lane];   // global, L1-hot broadcast
#pragma unroll
      for (int rt = 0; rt < 4; rt++)
        a2[rt] = __builtin_amdgcn_mfma_f32_16x16x32_bf16(
            Af, __builtin_bit_cast(s8v, bbv[rt][ks]), a2[rt], 0, 0, 0);
    }
    float4 w3v = ((const float4*)W3)[h2 * 4 + q4];   // global, L1-hot
#pragma unroll
    for (int rt = 0; rt < 4; rt++) {
      s[rt] += fmaxf(a2[rt][0], 0.f) * w3v.x;
      s[rt] += fmaxf(a2[rt][1], 0.f) * w3v.y;
      s[rt] += fmaxf(a2[rt][2], 0.f) * w3v.z;
      s[rt] += fmaxf(a2[rt][3], 0.f) * w3v.w;
    }
  }

  // ---- layer-3 reduce + local-ensemble combine (area via same-wave shfl) ----
  const float b3s = b3[0];
#pragma unroll
  for (int rt = 0; rt < 4; rt++) {
    float pred = s[rt];
    pred += __shfl_xor(pred, 16, 64);
    pred += __shfl_xor(pred, 32, 64);
    pred += b3s;
    float other = __shfl_xor(pred, 1, 64);   // (pass0, pass1) at adjacent l15
    float a0 = __shfl(area, rt * 16 + l15, 64);       // rows live in this wave
    float a1 = __shfl(area, rt * 16 + l15 + 1, 64);
    if (q4 == 0 && (l15 & 1) == 0) {
      int row0 = rt * 16 + l15;
      float tot = a0 + a1;
      // local_ensemble swap: pred(vx=-2)*a1/tot + pred(vx=0)*a0/tot
      out[(bid * 64 + row0) >> 1] = pred * (a1 / tot) + other * (a0 / tot);
    }
  }
}

extern "C" void kernel_launch(void* const* d_in, const int* in_sizes, int n_in,
                              void* d_out, int out_size, void* d_ws, size_t ws_size,
                              hipStream_t stream) {
  const float* coord  = (const float*)d_in[0];
  const float* latent = (const float*)d_in[1];
  const float* W1 = (const float*)d_in[2];
  const float* b1 = (const float*)d_in[3];
  const float* W2 = (const float*)d_in[4];
  const float* b2 = (const float*)d_in[5];
  const float* W3 = (const float*)d_in[6];
  const float* b3 = (const float*)d_in[7];
  float* out = (float*)d_out;
  unsigned short* wsW = (unsigned short*)d_ws;   // W1f | W2f | latbf

  prep_kernel<<<608, 256, 0, stream>>>(W1, b1, W2, latent, wsW);
  lisagon_main<<<8192, 64, 0, stream>>>(coord, wsW + 24576, wsW, wsW + 8192,
                                        b2, W3, b3, out);
}

// Round 4
// 117.155 us; speedup vs baseline: 1.1987x; 1.1987x over previous
//
#include <hip/hip_runtime.h>
#include <hip/hip_bf16.h>

typedef short s8v __attribute__((ext_vector_type(8)));      // 8 bf16 (4 VGPRs) MFMA A/B frag
typedef float f4v __attribute__((ext_vector_type(4)));      // MFMA C/D frag
typedef unsigned u4v __attribute__((ext_vector_type(4)));   // 4 packed bf16-pairs

__device__ __forceinline__ unsigned short f2bf(float x) {  // RTNE fp32->bf16 (prep only)
  unsigned u = __builtin_bit_cast(unsigned, x);
  u += 0x7fffu + ((u >> 16) & 1u);
  return (unsigned short)(u >> 16);
}
// pack 2 fp32 -> packed bf16 pair {lo=a, hi=b}
#if __has_builtin(__builtin_amdgcn_cvt_pk_bf16_f32)
__device__ __forceinline__ unsigned pk2(float a, float b) {
  return __builtin_bit_cast(unsigned, __builtin_amdgcn_cvt_pk_bf16_f32(a, b));
}
#else
__device__ __forceinline__ unsigned pk2(float a, float b) {  // 3 VALU ops, round-away
  unsigned ua = __builtin_bit_cast(unsigned, a) + 0x8000u;
  unsigned ub = __builtin_bit_cast(unsigned, b) + 0x8000u;
  return __builtin_amdgcn_perm(ub, ua, 0x07060302u);  // {ub.hi16, ua.hi16}
}
#endif

// ---------------- prep: W1f/W2f fragment packs + latent->bf16 table ----------------
// ws layout (unsigned short): [0,8192) W1f, [8192,24576) W2f, [24576,+524288) latbf.
// (unchanged from R16 baseline)
__global__ void prep_kernel(const float* __restrict__ W1, const float* __restrict__ b1,
                            const float* __restrict__ W2, const float* __restrict__ latent,
                            unsigned short* __restrict__ wsW) {
  int e = blockIdx.x * 256 + threadIdx.x;   // 608*256 = 155648 = 24576 + 131072
  if (e < 8192) {
    int frag = e >> 9, rem = e & 511, lane = rem >> 3, j = rem & 7;
    int h = frag >> 1, ks = frag & 1;
    int q4 = lane >> 4, l15 = lane & 15;
    int k = ks * 32 + q4 * 8 + j;
    int n = h * 16 + l15;
    float v;
    if (k < 13) v = W1[k * 128 + n];
    else if (k == 13) v = b1[n];
    else if (k < 16) v = 0.0f;
    else v = W1[(k - 3) * 128 + n];
    wsW[e] = f2bf(v);
  } else if (e < 24576) {
    int e2 = e - 8192;
    int frag = e2 >> 9, rem = e2 & 511, lane = rem >> 3, j = rem & 7;
    int h2 = frag >> 2, ks = frag & 3;
    int q4 = lane >> 4, l15 = lane & 15;
    int kd = (j < 4) ? (32 * ks + 4 * q4 + j) : (32 * ks + 16 + 4 * q4 + (j - 4));
    int n = h2 * 16 + l15;
    wsW[e] = f2bf(W2[kd * 128 + n]);
  } else {
    int i = e - 24576;                      // 4 floats -> 2 dwords, coalesced
    float4 v = ((const float4*)latent)[i];
    uint2 o;
    o.x = pk2(v.x, v.y);
    o.y = pk2(v.z, v.w);
    ((uint2*)(wsW + 24576))[i] = o;
  }
}

// ---------------- main fused kernel (R19: 1-wave blocks + sane reg budget) ----------
// R18 POST-MORTEM: VGPR_Count=64 + 240MB scratch traffic/dispatch -> spill-BW-bound
// (80us at 3TB/s). Cause: no __launch_bounds__ on a 64-thread kernel -> compiler
// assumes 1024-thread WGs -> 16 waves/WG co-residency -> 128 budget -> 64 arch +
// 64 acc -> everything spills. FIX (R19): __launch_bounds__(64) declares 1-wave
// WGs; compiler allocates the ~150 VGPRs actually needed. NO min-waves arg (that
// triggered the 50/50 split pathology in R17). Structure unchanged from R18:
// fully decoupled 1-wave blocks, zero __syncthreads, weights direct from L1/L2,
// PE via 2KB LDS (same-wave lgkmcnt-ordered).
__global__ __launch_bounds__(64) void lisagon_main(
    const float* __restrict__ coord, const unsigned short* __restrict__ latbf,
    const unsigned short* __restrict__ W1f, const unsigned short* __restrict__ W2f,
    const float* __restrict__ b2, const float* __restrict__ W3,
    const float* __restrict__ b3, float* __restrict__ out) {
  __shared__ __align__(16) unsigned PE[2][64][4];          // 2 KB: 2 planes x 64 rows

  const int t = threadIdx.x;                // 0..63, == lane
  const int lane = t;
  const int l15 = lane & 15, q4 = lane >> 4;
  // XCD-aware swizzle (bijective on [0,8192)): phys blocks with i%8 in {2j,2j+1}
  // (one XCD pair under round-robin) land in batch j = bid>>11. Each XCD serves
  // ONE batch (~260 KB L2 working set). Speed-only heuristic (G16-safe).
  const int bid = ((blockIdx.x & 7) >> 1) * 2048 + ((blockIdx.x >> 3) << 1) + (blockIdx.x & 1);

  // ---- phase 0: idx + area + PE for row t (all 64 lanes dense) ----
  int idx;
  float area;
  {
    const int Rg = bid * 64 + t;
    const int gq = Rg >> 1, p = Rg & 1;       // p=0 -> vx=-2 pass, p=1 -> vx=0 pass
    const float co = coord[gq];
    float c = (co + (p ? 0.0f : -0.000244140625f)) + 1e-6f;  // vx*rx exact
    c = fminf(fmaxf(c, -1.0f + 1e-6f), 1.0f - 1e-6f);
    double u = ((double)c * 8192.0 + 8191.0) * 0.5;          // exact searchsorted
    idx = (int)ceil(u);
    idx = min(max(idx, 0), 8191);
    float qc = ((float)(2 * idx + 1) - 8192.0f) * (1.0f / 8192.0f);  // exact grid[idx]
    float rel = (co - qc) * 8192.0f;
    area = fabsf(rel) + 1e-9f;
    float v[16];
    v[0] = rel;
    float f = rel;
#pragma unroll
    for (int i = 0; i < 6; i++) {
      v[1 + 2 * i] = __sinf(f);
      v[2 + 2 * i] = __cosf(f);
      f = f + f;                 // exact power-of-2 freqs
    }
    v[13] = 1.0f;                // bias-fold slot (W1f input dim 13 = b1)
    v[14] = 0.0f; v[15] = 0.0f;
    uint4 q0, q1;
    q0.x = pk2(v[0], v[1]);   q0.y = pk2(v[2], v[3]);
    q0.z = pk2(v[4], v[5]);   q0.w = pk2(v[6], v[7]);
    q1.x = pk2(v[8], v[9]);   q1.y = pk2(v[10], v[11]);
    q1.z = pk2(v[12], v[13]); q1.w = pk2(v[14], v[15]);
    ((uint4*)PE[0])[t] = q0;   // plane 0: values 0..7 of row t
    ((uint4*)PE[1])[t] = q1;   // plane 1: values 8..15
  }

  // ---- per-lane direct B-fragment assembly (intra-wave only; NO barrier) ----
  // chunk map: ks0: q4<2 -> PE plane q4; q4>=2 -> prev, chunk q4&1. ks1: q4<2 ->
  // self, chunk q4&1; q4>=2 -> next, chunk q4&1.
  const size_t bbase = (size_t)(bid >> 11) * (8192 * 16);  // batch, WG-uniform
  const uint4* latv4 = (const uint4*)(latbf + bbase);   // row r chunk c = latv4[r*2+c]
  s8v Bf[2][4];
#pragma unroll
  for (int rt = 0; rt < 4; rt++) {
    int srcl = rt * 16 + l15;                // source lane (same wave) for this row
    int sidx = __shfl(idx, srcl, 64);
    int rp = max(sidx - 1, 0), rn = min(sidx + 1, 8191);
    int c = q4 & 1;
    uint4 g0 = latv4[rp * 2 + c];                        // ks0 chunk (q4>=2; dummy else)
    uint4 g1 = latv4[(q4 < 2 ? sidx : rn) * 2 + c];      // ks1 chunk
    uint4 pe = ((const uint4*)PE[c])[srcl];              // PE chunk (q4<2; dummy else)
    uint4 b0;
    b0.x = q4 < 2 ? pe.x : g0.x;  b0.y = q4 < 2 ? pe.y : g0.y;
    b0.z = q4 < 2 ? pe.z : g0.z;  b0.w = q4 < 2 ? pe.w : g0.w;
    Bf[0][rt] = __builtin_bit_cast(s8v, b0);
    Bf[1][rt] = __builtin_bit_cast(s8v, g1);
  }

  // ---- GEMM1' (h-outer): W1 frags loaded direct (each used once); relu+pack
  // DIRECTLY into bbv lanes. bbv[rt][ks] is GEMM2's B-fragment for K-chunk ks
  // (K-permuted to match W2f prep layout). ----
  const s8v* W1fv = (const s8v*)W1f;
  u4v bbv[4][4];
#pragma unroll
  for (int h = 0; h < 8; h++) {
    f4v a[4];
#pragma unroll
    for (int rt = 0; rt < 4; rt++) a[rt] = (f4v){0.f, 0.f, 0.f, 0.f};
#pragma unroll
    for (int ks = 0; ks < 2; ks++) {
      s8v w1 = W1fv[(h * 2 + ks) * 64 + lane];   // global, L1/L2-hot broadcast
#pragma unroll
      for (int rt = 0; rt < 4; rt++)
        a[rt] = __builtin_amdgcn_mfma_f32_16x16x32_bf16(w1, Bf[ks][rt], a[rt], 0, 0, 0);
    }
#pragma unroll
    for (int rt = 0; rt < 4; rt++) {
      bbv[rt][h >> 1][2 * (h & 1)]     = pk2(fmaxf(a[rt][0], 0.f), fmaxf(a[rt][1], 0.f));
      bbv[rt][h >> 1][2 * (h & 1) + 1] = pk2(fmaxf(a[rt][2], 0.f), fmaxf(a[rt][3], 0.f));
    }
  }

  // ---- GEMM2' (h2-outer, weights direct from global): b2 as acc-init ----
  const s8v* W2fv = (const s8v*)W2f;
  float s[4] = {0.f, 0.f, 0.f, 0.f};
#pragma unroll
  for (int h2 = 0; h2 < 8; h2++) {
    f4v a2[4];
    f4v b2v = ((const f4v*)b2)[h2 * 4 + q4];   // global, L1-hot; elem i -> 16h2+4q4+i
#pragma unroll
    for (int rt = 0; rt < 4; rt++) a2[rt] = b2v;
#pragma unroll
    for (int ks = 0; ks < 4; ks++) {
      s8v Af = W2fv[(h2 * 4 + ks) * 64 + lane];   // global, L1/L2-hot broadcast
#pragma unroll
      for (int rt = 0; rt < 4; rt++)
        a2[rt] = __builtin_amdgcn_mfma_f32_16x16x32_bf16(
            Af, __builtin_bit_cast(s8v, bbv[rt][ks]), a2[rt], 0, 0, 0);
    }
    float4 w3v = ((const float4*)W3)[h2 * 4 + q4];   // global, L1-hot
#pragma unroll
    for (int rt = 0; rt < 4; rt++) {
      s[rt] += fmaxf(a2[rt][0], 0.f) * w3v.x;
      s[rt] += fmaxf(a2[rt][1], 0.f) * w3v.y;
      s[rt] += fmaxf(a2[rt][2], 0.f) * w3v.z;
      s[rt] += fmaxf(a2[rt][3], 0.f) * w3v.w;
    }
  }

  // ---- layer-3 reduce + local-ensemble combine (area via same-wave shfl) ----
  const float b3s = b3[0];
#pragma unroll
  for (int rt = 0; rt < 4; rt++) {
    float pred = s[rt];
    pred += __shfl_xor(pred, 16, 64);
    pred += __shfl_xor(pred, 32, 64);
    pred += b3s;
    float other = __shfl_xor(pred, 1, 64);   // (pass0, pass1) at adjacent l15
    float a0 = __shfl(area, rt * 16 + l15, 64);       // rows live in this wave
    float a1 = __shfl(area, rt * 16 + l15 + 1, 64);
    if (q4 == 0 && (l15 & 1) == 0) {
      int row0 = rt * 16 + l15;
      float tot = a0 + a1;
      // local_ensemble swap: pred(vx=-2)*a1/tot + pred(vx=0)*a0/tot
      out[(bid * 64 + row0) >> 1] = pred * (a1 / tot) + other * (a0 / tot);
    }
  }
}

extern "C" void kernel_launch(void* const* d_in, const int* in_sizes, int n_in,
                              void* d_out, int out_size, void* d_ws, size_t ws_size,
                              hipStream_t stream) {
  const float* coord  = (const float*)d_in[0];
  const float* latent = (const float*)d_in[1];
  const float* W1 = (const float*)d_in[2];
  const float* b1 = (const float*)d_in[3];
  const float* W2 = (const float*)d_in[4];
  const float* b2 = (const float*)d_in[5];
  const float* W3 = (const float*)d_in[6];
  const float* b3 = (const float*)d_in[7];
  float* out = (float*)d_out;
  unsigned short* wsW = (unsigned short*)d_ws;   // W1f | W2f | latbf

  prep_kernel<<<608, 256, 0, stream>>>(W1, b1, W2, latent, wsW);
  lisagon_main<<<8192, 64, 0, stream>>>(coord, wsW + 24576, wsW, wsW + 8192,
                                        b2, W3, b3, out);
}

// Round 5
// 97.491 us; speedup vs baseline: 1.4404x; 1.2017x over previous
//
#include <hip/hip_runtime.h>
#include <hip/hip_bf16.h>

typedef short s8v __attribute__((ext_vector_type(8)));      // 8 bf16 (4 VGPRs) MFMA A/B frag
typedef float f4v __attribute__((ext_vector_type(4)));      // MFMA C/D frag
typedef unsigned u4v __attribute__((ext_vector_type(4)));   // 4 packed bf16-pairs

__device__ __forceinline__ unsigned short f2bf(float x) {  // RTNE fp32->bf16 (prep only)
  unsigned u = __builtin_bit_cast(unsigned, x);
  u += 0x7fffu + ((u >> 16) & 1u);
  return (unsigned short)(u >> 16);
}
// pack 2 fp32 -> packed bf16 pair {lo=a, hi=b}
#if __has_builtin(__builtin_amdgcn_cvt_pk_bf16_f32)
__device__ __forceinline__ unsigned pk2(float a, float b) {
  return __builtin_bit_cast(unsigned, __builtin_amdgcn_cvt_pk_bf16_f32(a, b));
}
#else
__device__ __forceinline__ unsigned pk2(float a, float b) {  // 3 VALU ops, round-away
  unsigned ua = __builtin_bit_cast(unsigned, a) + 0x8000u;
  unsigned ub = __builtin_bit_cast(unsigned, b) + 0x8000u;
  return __builtin_amdgcn_perm(ub, ua, 0x07060302u);  // {ub.hi16, ua.hi16}
}
#endif

// async global->LDS DMA, 16 B per lane; LDS dest = wave-uniform base + lane*16
__device__ __forceinline__ void g2lds16(const void* g, void* l) {
  __builtin_amdgcn_global_load_lds(
      (const __attribute__((address_space(1))) unsigned*)g,
      (__attribute__((address_space(3))) unsigned*)l, 16, 0, 0);
}

// ---------------- prep: W1f/W2f fragment packs + latent->bf16 table ----------------
// ws layout (unsigned short): [0,8192) W1f, [8192,24576) W2f, [24576,+524288) latbf.
// (unchanged from R16 baseline)
__global__ void prep_kernel(const float* __restrict__ W1, const float* __restrict__ b1,
                            const float* __restrict__ W2, const float* __restrict__ latent,
                            unsigned short* __restrict__ wsW) {
  int e = blockIdx.x * 256 + threadIdx.x;   // 608*256 = 155648 = 24576 + 131072
  if (e < 8192) {
    int frag = e >> 9, rem = e & 511, lane = rem >> 3, j = rem & 7;
    int h = frag >> 1, ks = frag & 1;
    int q4 = lane >> 4, l15 = lane & 15;
    int k = ks * 32 + q4 * 8 + j;
    int n = h * 16 + l15;
    float v;
    if (k < 13) v = W1[k * 128 + n];
    else if (k == 13) v = b1[n];
    else if (k < 16) v = 0.0f;
    else v = W1[(k - 3) * 128 + n];
    wsW[e] = f2bf(v);
  } else if (e < 24576) {
    int e2 = e - 8192;
    int frag = e2 >> 9, rem = e2 & 511, lane = rem >> 3, j = rem & 7;
    int h2 = frag >> 2, ks = frag & 3;
    int q4 = lane >> 4, l15 = lane & 15;
    int kd = (j < 4) ? (32 * ks + 4 * q4 + j) : (32 * ks + 16 + 4 * q4 + (j - 4));
    int n = h2 * 16 + l15;
    wsW[e] = f2bf(W2[kd * 128 + n]);
  } else {
    int i = e - 24576;                      // 4 floats -> 2 dwords, coalesced
    float4 v = ((const float4*)latent)[i];
    uint2 o;
    o.x = pk2(v.x, v.y);
    o.y = pk2(v.z, v.w);
    ((uint2*)(wsW + 24576))[i] = o;
  }
}

// ---------------- main fused kernel (R20: slim waves, high occupancy) ----------------
// R19 POST-MORTEM: no spill, VGPR=132(arch)+acc -> ~1 wave/SIMD resident
// (Occupancy 9.9%); main 55us = pure exposed latency (compute floor ~4us).
// R20: R17's verified rt=2 wave code (32 rows/wave, 256-thr/4-wave WG, grid 4096)
// with the W1r[16] register preload REMOVED (-64 VGPRs; GEMM1 reads each W1 frag
// once from global, L1-hot broadcast -- R19 proved the path). LDS = W2s 32K +
// PE 4K + BW 1K = 37KB -> up to 4 WG/CU. __launch_bounds__(256,2) (R16-proven,
// budget 256 >> natural ~120 -> no 50/50 split, no spill). Expect 3-4 waves/SIMD.
__global__ __launch_bounds__(256, 2) void lisagon_main(
    const float* __restrict__ coord, const unsigned short* __restrict__ latbf,
    const unsigned short* __restrict__ W1f, const unsigned short* __restrict__ W2f,
    const float* __restrict__ b2, const float* __restrict__ W3,
    const float* __restrict__ b3, float* __restrict__ out) {
  __shared__ __align__(16) unsigned short W2s[16384];      // 32 KB W2 fragments
  __shared__ __align__(16) unsigned PE[2][128][4];         // 4 KB: 2 planes x 128 rows
  __shared__ __align__(16) float BW[256];                  // b2 [0,128) | W3 [128,256)

  const int t = threadIdx.x;
  const int lane = t & 63, wv = t >> 6;
  const int l15 = lane & 15, q4 = lane >> 4;
  // XCD-aware swizzle (bijective on [0,4096)): phys blocks i%8 in {2j,2j+1} (one XCD
  // under round-robin) land in batch j = bid>>10. Speed-only heuristic (G16-safe).
  const int bid = ((blockIdx.x & 7) >> 1) * 1024 + ((blockIdx.x >> 3) << 1) + (blockIdx.x & 1);

  // ---- issue W2f -> LDS DMA first (covered until the post-GEMM1 barrier) ----
#pragma unroll
  for (int it = 0; it < 8; it++) {
    int off = (it * 4 + wv) * 1024;          // bytes; wave-uniform LDS base
    g2lds16((const char*)W2f + off + lane * 16, (char*)W2s + off);
  }
  // ---- stage b2 / W3 into LDS (1 KB; visible after the barrier) ----
  if (t < 64) {
    ((float4*)BW)[t] = (t < 32) ? ((const float4*)b2)[t] : ((const float4*)W3)[t - 32];
  }

  // ---- phase 0 (lite): idx + area + PE for the wave's own 32 rows ----
  // lanes 0-31 of wave wv handle rows rbase..rbase+31 (rbase = 32*wv); lanes 32-63
  // idle here. Same-wave write->read on PE (lgkmcnt-ordered, NO barrier).
  const int rbase = wv * 32;
  int idx = 0;
  float area = 0.0f;
  if (lane < 32) {
    const int row = rbase + lane;            // row within block
    const int Rg = bid * 128 + row;
    const int gq = Rg >> 1, p = Rg & 1;      // p=0 -> vx=-2 pass, p=1 -> vx=0 pass
    const float co = coord[gq];
    float c = (co + (p ? 0.0f : -0.000244140625f)) + 1e-6f;  // vx*rx exact
    c = fminf(fmaxf(c, -1.0f + 1e-6f), 1.0f - 1e-6f);
    double u = ((double)c * 8192.0 + 8191.0) * 0.5;          // exact searchsorted
    idx = (int)ceil(u);
    idx = min(max(idx, 0), 8191);
    float qc = ((float)(2 * idx + 1) - 8192.0f) * (1.0f / 8192.0f);  // exact grid[idx]
    float rel = (co - qc) * 8192.0f;
    area = fabsf(rel) + 1e-9f;
    float v[16];
    v[0] = rel;
    float f = rel;
#pragma unroll
    for (int i = 0; i < 6; i++) {
      v[1 + 2 * i] = __sinf(f);
      v[2 + 2 * i] = __cosf(f);
      f = f + f;                 // exact power-of-2 freqs
    }
    v[13] = 1.0f;                // bias-fold slot (W1f input dim 13 = b1)
    v[14] = 0.0f; v[15] = 0.0f;
    uint4 q0, q1;
    q0.x = pk2(v[0], v[1]);   q0.y = pk2(v[2], v[3]);
    q0.z = pk2(v[4], v[5]);   q0.w = pk2(v[6], v[7]);
    q1.x = pk2(v[8], v[9]);   q1.y = pk2(v[10], v[11]);
    q1.z = pk2(v[12], v[13]); q1.w = pk2(v[14], v[15]);
    ((uint4*)PE[0])[row] = q0;   // plane 0: values 0..7 of row
    ((uint4*)PE[1])[row] = q1;   // plane 1: values 8..15
  }

  // ---- per-lane direct B-fragment assembly (intra-wave only; NO barrier) ----
  // chunk map: ks0: q4<2 -> PE plane q4; q4>=2 -> prev, chunk q4&1. ks1: q4<2 ->
  // self, chunk q4&1; q4>=2 -> next, chunk q4&1.
  const size_t bbase = (size_t)(bid >> 10) * (8192 * 16);  // batch, WG-uniform
  const uint4* latv4 = (const uint4*)(latbf + bbase);   // row r chunk c = latv4[r*2+c]
  s8v Bf[2][2];
#pragma unroll
  for (int rt = 0; rt < 2; rt++) {
    int srcl = rt * 16 + l15;                // source lane (same wave, <32) for this row
    int sidx = __shfl(idx, srcl, 64);
    int rp = max(sidx - 1, 0), rn = min(sidx + 1, 8191);
    int c = q4 & 1;
    uint4 g0 = latv4[rp * 2 + c];                        // ks0 chunk (q4>=2; dummy else)
    uint4 g1 = latv4[(q4 < 2 ? sidx : rn) * 2 + c];      // ks1 chunk
    uint4 pe = ((const uint4*)PE[c])[rbase + srcl];      // PE chunk (q4<2; dummy else)
    uint4 b0;
    b0.x = q4 < 2 ? pe.x : g0.x;  b0.y = q4 < 2 ? pe.y : g0.y;
    b0.z = q4 < 2 ? pe.z : g0.z;  b0.w = q4 < 2 ? pe.w : g0.w;
    Bf[0][rt] = __builtin_bit_cast(s8v, b0);
    Bf[1][rt] = __builtin_bit_cast(s8v, g1);
  }

  // ---- GEMM1' (h-outer): W1 frags direct from global (each used once, L1-hot
  // broadcast -- no 64-VGPR preload); relu+pack DIRECTLY into bbv lanes.
  // bbv[rt][ks] is GEMM2's B-fragment for K-chunk ks (K-permuted to match W2f). ----
  const s8v* W1fv = (const s8v*)W1f;
  u4v bbv[2][4];
#pragma unroll
  for (int h = 0; h < 8; h++) {
    f4v a[2];
#pragma unroll
    for (int rt = 0; rt < 2; rt++) a[rt] = (f4v){0.f, 0.f, 0.f, 0.f};
#pragma unroll
    for (int ks = 0; ks < 2; ks++) {
      s8v w1 = W1fv[(h * 2 + ks) * 64 + lane];   // global, L1-hot broadcast
#pragma unroll
      for (int rt = 0; rt < 2; rt++)
        a[rt] = __builtin_amdgcn_mfma_f32_16x16x32_bf16(w1, Bf[ks][rt], a[rt], 0, 0, 0);
    }
#pragma unroll
    for (int rt = 0; rt < 2; rt++) {
      bbv[rt][h >> 1][2 * (h & 1)]     = pk2(fmaxf(a[rt][0], 0.f), fmaxf(a[rt][1], 0.f));
      bbv[rt][h >> 1][2 * (h & 1) + 1] = pk2(fmaxf(a[rt][2], 0.f), fmaxf(a[rt][3], 0.f));
    }
  }

  __syncthreads();   // W2s DMA + BW visibility (GEMM1 already consumed Bf)

  // ---- GEMM2' (h2-outer, weights from LDS): b2 as acc-init; consume into dot ----
  const s8v* W2sv = (const s8v*)W2s;
  float s[2] = {0.f, 0.f};
#pragma unroll
  for (int h2 = 0; h2 < 8; h2++) {
    f4v a2[2];
    f4v b2v = ((const f4v*)BW)[h2 * 4 + q4];   // LDS broadcast; elem i -> h2 16h2+4q4+i
#pragma unroll
    for (int rt = 0; rt < 2; rt++) a2[rt] = b2v;
#pragma unroll
    for (int ks = 0; ks < 4; ks++) {
      s8v Af = W2sv[(h2 * 4 + ks) * 64 + lane];   // ds_read_b128, conflict-free
#pragma unroll
      for (int rt = 0; rt < 2; rt++)
        a2[rt] = __builtin_amdgcn_mfma_f32_16x16x32_bf16(
            Af, __builtin_bit_cast(s8v, bbv[rt][ks]), a2[rt], 0, 0, 0);
    }
    float4 w3v = ((const float4*)(BW + 128))[h2 * 4 + q4];   // LDS broadcast
#pragma unroll
    for (int rt = 0; rt < 2; rt++) {
      s[rt] += fmaxf(a2[rt][0], 0.f) * w3v.x;
      s[rt] += fmaxf(a2[rt][1], 0.f) * w3v.y;
      s[rt] += fmaxf(a2[rt][2], 0.f) * w3v.z;
      s[rt] += fmaxf(a2[rt][3], 0.f) * w3v.w;
    }
  }

  // ---- layer-3 reduce + local-ensemble combine (area via same-wave shfl) ----
  const float b3s = b3[0];
#pragma unroll
  for (int rt = 0; rt < 2; rt++) {
    float pred = s[rt];
    pred += __shfl_xor(pred, 16, 64);
    pred += __shfl_xor(pred, 32, 64);
    pred += b3s;
    float other = __shfl_xor(pred, 1, 64);   // (pass0, pass1) at adjacent l15
    float a0 = __shfl(area, rt * 16 + l15, 64);       // rows live in lanes 0-31
    float a1 = __shfl(area, rt * 16 + l15 + 1, 64);
    if (q4 == 0 && (l15 & 1) == 0) {
      int row0 = rbase + rt * 16 + l15;
      float tot = a0 + a1;
      // local_ensemble swap: pred(vx=-2)*a1/tot + pred(vx=0)*a0/tot
      out[(bid * 128 + row0) >> 1] = pred * (a1 / tot) + other * (a0 / tot);
    }
  }
}

extern "C" void kernel_launch(void* const* d_in, const int* in_sizes, int n_in,
                              void* d_out, int out_size, void* d_ws, size_t ws_size,
                              hipStream_t stream) {
  const float* coord  = (const float*)d_in[0];
  const float* latent = (const float*)d_in[1];
  const float* W1 = (const float*)d_in[2];
  const float* b1 = (const float*)d_in[3];
  const float* W2 = (const float*)d_in[4];
  const float* b2 = (const float*)d_in[5];
  const float* W3 = (const float*)d_in[6];
  const float* b3 = (const float*)d_in[7];
  float* out = (float*)d_out;
  unsigned short* wsW = (unsigned short*)d_ws;   // W1f | W2f | latbf

  prep_kernel<<<608, 256, 0, stream>>>(W1, b1, W2, latent, wsW);
  lisagon_main<<<4096, 256, 0, stream>>>(coord, wsW + 24576, wsW, wsW + 8192,
                                         b2, W3, b3, out);
}

// Round 6
// 97.483 us; speedup vs baseline: 1.4406x; 1.0001x over previous
//
#include <hip/hip_runtime.h>
#include <hip/hip_bf16.h>

typedef short s8v __attribute__((ext_vector_type(8)));      // 8 bf16 (4 VGPRs) MFMA A/B frag
typedef float f4v __attribute__((ext_vector_type(4)));      // MFMA C/D frag
typedef unsigned u4v __attribute__((ext_vector_type(4)));   // 4 packed bf16-pairs

__device__ __forceinline__ unsigned short f2bf(float x) {  // RTNE fp32->bf16 (prep only)
  unsigned u = __builtin_bit_cast(unsigned, x);
  u += 0x7fffu + ((u >> 16) & 1u);
  return (unsigned short)(u >> 16);
}
// pack 2 fp32 -> packed bf16 pair {lo=a, hi=b}
#if __has_builtin(__builtin_amdgcn_cvt_pk_bf16_f32)
__device__ __forceinline__ unsigned pk2(float a, float b) {
  return __builtin_bit_cast(unsigned, __builtin_amdgcn_cvt_pk_bf16_f32(a, b));
}
#else
__device__ __forceinline__ unsigned pk2(float a, float b) {  // 3 VALU ops, round-away
  unsigned ua = __builtin_bit_cast(unsigned, a) + 0x8000u;
  unsigned ub = __builtin_bit_cast(unsigned, b) + 0x8000u;
  return __builtin_amdgcn_perm(ub, ua, 0x07060302u);  // {ub.hi16, ua.hi16}
}
#endif

// async global->LDS DMA, 16 B per lane; LDS dest = wave-uniform base + lane*16
__device__ __forceinline__ void g2lds16(const void* g, void* l) {
  __builtin_amdgcn_global_load_lds(
      (const __attribute__((address_space(1))) unsigned*)g,
      (__attribute__((address_space(3))) unsigned*)l, 16, 0, 0);
}

// ---------------- prep: W1f/W2f fragment packs + latent->bf16 table ----------------
// ws layout (unsigned short): [0,8192) W1f, [8192,24576) W2f, [24576,+524288) latbf.
// (unchanged from R16 baseline)
__global__ void prep_kernel(const float* __restrict__ W1, const float* __restrict__ b1,
                            const float* __restrict__ W2, const float* __restrict__ latent,
                            unsigned short* __restrict__ wsW) {
  int e = blockIdx.x * 256 + threadIdx.x;   // 608*256 = 155648 = 24576 + 131072
  if (e < 8192) {
    int frag = e >> 9, rem = e & 511, lane = rem >> 3, j = rem & 7;
    int h = frag >> 1, ks = frag & 1;
    int q4 = lane >> 4, l15 = lane & 15;
    int k = ks * 32 + q4 * 8 + j;
    int n = h * 16 + l15;
    float v;
    if (k < 13) v = W1[k * 128 + n];
    else if (k == 13) v = b1[n];
    else if (k < 16) v = 0.0f;
    else v = W1[(k - 3) * 128 + n];
    wsW[e] = f2bf(v);
  } else if (e < 24576) {
    int e2 = e - 8192;
    int frag = e2 >> 9, rem = e2 & 511, lane = rem >> 3, j = rem & 7;
    int h2 = frag >> 2, ks = frag & 3;
    int q4 = lane >> 4, l15 = lane & 15;
    int kd = (j < 4) ? (32 * ks + 4 * q4 + j) : (32 * ks + 16 + 4 * q4 + (j - 4));
    int n = h2 * 16 + l15;
    wsW[e] = f2bf(W2[kd * 128 + n]);
  } else {
    int i = e - 24576;                      // 4 floats -> 2 dwords, coalesced
    float4 v = ((const float4*)latent)[i];
    uint2 o;
    o.x = pk2(v.x, v.y);
    o.y = pk2(v.z, v.w);
    ((uint2*)(wsW + 24576))[i] = o;
  }
}

// ---------------- main fused kernel (R21: 8-wave WGs, slim waves) ----------------
// THEORY (R21): residency looks WG-slot-limited (~2-3 WGs/CU in flight regardless
// of WG size: R19's 1-wave WGs ran at 3.2 waves/CU despite VGPR/LDS allowing 15+).
// So waves/CU ~ WGslots x waves_per_WG -> grow the WG, slim the wave. 512 thr =
// 8 waves/WG, 256 rows/WG (rt=2/wave), grid 2048. No W1r preload (R19/R20-proven
// global L1-hot path). W2s DMA + single post-GEMM1 barrier. lb(512,2): budget 256
// >> natural ~110 -> no 50/50-split; if natural VGPR <=128 -> 2 WG/CU = 16
// waves/CU = 4/SIMD (2x R16). LDS 41KB x 2 = 82KB ok.
__global__ __launch_bounds__(512, 2) void lisagon_main(
    const float* __restrict__ coord, const unsigned short* __restrict__ latbf,
    const unsigned short* __restrict__ W1f, const unsigned short* __restrict__ W2f,
    const float* __restrict__ b2, const float* __restrict__ W3,
    const float* __restrict__ b3, float* __restrict__ out) {
  __shared__ __align__(16) unsigned short W2s[16384];      // 32 KB W2 fragments
  __shared__ __align__(16) unsigned PE[2][256][4];         // 8 KB: 2 planes x 256 rows
  __shared__ __align__(16) float BW[256];                  // b2 [0,128) | W3 [128,256)

  const int t = threadIdx.x;
  const int lane = t & 63, wv = t >> 6;     // wv in [0,8)
  const int l15 = lane & 15, q4 = lane >> 4;
  // XCD-aware swizzle (bijective on [0,2048)): physical blocks i%8==j (one XCD under
  // round-robin) all land in batch j>>1. Speed-only heuristic (G16-safe).
  const int bid = ((blockIdx.x & 7) >> 1) * 512 + ((blockIdx.x >> 3) << 1) + (blockIdx.x & 1);

  // ---- issue W2f -> LDS DMA first (covered until the post-GEMM1 barrier) ----
  // 32 KB total, 512 lanes x 16 B = 8 KB per pass -> 4 passes.
#pragma unroll
  for (int it = 0; it < 4; it++) {
    int off = (it * 8 + wv) * 1024;          // bytes; wave-uniform LDS base
    g2lds16((const char*)W2f + off + lane * 16, (char*)W2s + off);
  }
  // ---- stage b2 / W3 into LDS (1 KB; visible after the barrier) ----
  if (t < 64) {
    ((float4*)BW)[t] = (t < 32) ? ((const float4*)b2)[t] : ((const float4*)W3)[t - 32];
  }

  // ---- phase 0 (lite): idx + area + PE for the wave's own 32 rows ----
  // lanes 0-31 of wave wv handle rows rbase..rbase+31 (rbase = 32*wv); lanes 32-63
  // idle here. Same-wave write->read on PE (lgkmcnt-ordered, NO barrier).
  const int rbase = wv * 32;
  int idx = 0;
  float area = 0.0f;
  if (lane < 32) {
    const int row = rbase + lane;            // row within block
    const int Rg = bid * 256 + row;
    const int gq = Rg >> 1, p = Rg & 1;      // p=0 -> vx=-2 pass, p=1 -> vx=0 pass
    const float co = coord[gq];
    float c = (co + (p ? 0.0f : -0.000244140625f)) + 1e-6f;  // vx*rx exact
    c = fminf(fmaxf(c, -1.0f + 1e-6f), 1.0f - 1e-6f);
    double u = ((double)c * 8192.0 + 8191.0) * 0.5;          // exact searchsorted
    idx = (int)ceil(u);
    idx = min(max(idx, 0), 8191);
    float qc = ((float)(2 * idx + 1) - 8192.0f) * (1.0f / 8192.0f);  // exact grid[idx]
    float rel = (co - qc) * 8192.0f;
    area = fabsf(rel) + 1e-9f;
    float v[16];
    v[0] = rel;
    float f = rel;
#pragma unroll
    for (int i = 0; i < 6; i++) {
      v[1 + 2 * i] = __sinf(f);
      v[2 + 2 * i] = __cosf(f);
      f = f + f;                 // exact power-of-2 freqs
    }
    v[13] = 1.0f;                // bias-fold slot (W1f input dim 13 = b1)
    v[14] = 0.0f; v[15] = 0.0f;
    uint4 q0, q1;
    q0.x = pk2(v[0], v[1]);   q0.y = pk2(v[2], v[3]);
    q0.z = pk2(v[4], v[5]);   q0.w = pk2(v[6], v[7]);
    q1.x = pk2(v[8], v[9]);   q1.y = pk2(v[10], v[11]);
    q1.z = pk2(v[12], v[13]); q1.w = pk2(v[14], v[15]);
    ((uint4*)PE[0])[row] = q0;   // plane 0: values 0..7 of row
    ((uint4*)PE[1])[row] = q1;   // plane 1: values 8..15
  }

  // ---- per-lane direct B-fragment assembly (intra-wave only; NO barrier) ----
  // chunk map: ks0: q4<2 -> PE plane q4; q4>=2 -> prev, chunk q4&1. ks1: q4<2 ->
  // self, chunk q4&1; q4>=2 -> next, chunk q4&1.
  const size_t bbase = (size_t)(bid >> 9) * (8192 * 16);   // batch, WG-uniform
  const uint4* latv4 = (const uint4*)(latbf + bbase);   // row r chunk c = latv4[r*2+c]
  s8v Bf[2][2];
#pragma unroll
  for (int rt = 0; rt < 2; rt++) {
    int srcl = rt * 16 + l15;                // source lane (same wave, <32) for this row
    int sidx = __shfl(idx, srcl, 64);
    int rp = max(sidx - 1, 0), rn = min(sidx + 1, 8191);
    int c = q4 & 1;
    uint4 g0 = latv4[rp * 2 + c];                        // ks0 chunk (q4>=2; dummy else)
    uint4 g1 = latv4[(q4 < 2 ? sidx : rn) * 2 + c];      // ks1 chunk
    uint4 pe = ((const uint4*)PE[c])[rbase + srcl];      // PE chunk (q4<2; dummy else)
    uint4 b0;
    b0.x = q4 < 2 ? pe.x : g0.x;  b0.y = q4 < 2 ? pe.y : g0.y;
    b0.z = q4 < 2 ? pe.z : g0.z;  b0.w = q4 < 2 ? pe.w : g0.w;
    Bf[0][rt] = __builtin_bit_cast(s8v, b0);
    Bf[1][rt] = __builtin_bit_cast(s8v, g1);
  }

  // ---- GEMM1' (h-outer): W1 frags direct from global (each used once, L1-hot
  // broadcast); relu+pack DIRECTLY into bbv lanes. bbv[rt][ks] is GEMM2's
  // B-fragment for K-chunk ks (K-permuted to match W2f prep layout). ----
  const s8v* W1fv = (const s8v*)W1f;
  u4v bbv[2][4];
#pragma unroll
  for (int h = 0; h < 8; h++) {
    f4v a[2];
#pragma unroll
    for (int rt = 0; rt < 2; rt++) a[rt] = (f4v){0.f, 0.f, 0.f, 0.f};
#pragma unroll
    for (int ks = 0; ks < 2; ks++) {
      s8v w1 = W1fv[(h * 2 + ks) * 64 + lane];   // global, L1-hot broadcast
#pragma unroll
      for (int rt = 0; rt < 2; rt++)
        a[rt] = __builtin_amdgcn_mfma_f32_16x16x32_bf16(w1, Bf[ks][rt], a[rt], 0, 0, 0);
    }
#pragma unroll
    for (int rt = 0; rt < 2; rt++) {
      bbv[rt][h >> 1][2 * (h & 1)]     = pk2(fmaxf(a[rt][0], 0.f), fmaxf(a[rt][1], 0.f));
      bbv[rt][h >> 1][2 * (h & 1) + 1] = pk2(fmaxf(a[rt][2], 0.f), fmaxf(a[rt][3], 0.f));
    }
  }

  __syncthreads();   // W2s DMA + BW visibility (GEMM1 already consumed Bf)

  // ---- GEMM2' (h2-outer, weights from LDS): b2 as acc-init; consume into dot ----
  const s8v* W2sv = (const s8v*)W2s;
  float s[2] = {0.f, 0.f};
#pragma unroll
  for (int h2 = 0; h2 < 8; h2++) {
    f4v a2[2];
    f4v b2v = ((const f4v*)BW)[h2 * 4 + q4];   // LDS broadcast; elem i -> h2 16h2+4q4+i
#pragma unroll
    for (int rt = 0; rt < 2; rt++) a2[rt] = b2v;
#pragma unroll
    for (int ks = 0; ks < 4; ks++) {
      s8v Af = W2sv[(h2 * 4 + ks) * 64 + lane];   // ds_read_b128, conflict-free
#pragma unroll
      for (int rt = 0; rt < 2; rt++)
        a2[rt] = __builtin_amdgcn_mfma_f32_16x16x32_bf16(
            Af, __builtin_bit_cast(s8v, bbv[rt][ks]), a2[rt], 0, 0, 0);
    }
    float4 w3v = ((const float4*)(BW + 128))[h2 * 4 + q4];   // LDS broadcast
#pragma unroll
    for (int rt = 0; rt < 2; rt++) {
      s[rt] += fmaxf(a2[rt][0], 0.f) * w3v.x;
      s[rt] += fmaxf(a2[rt][1], 0.f) * w3v.y;
      s[rt] += fmaxf(a2[rt][2], 0.f) * w3v.z;
      s[rt] += fmaxf(a2[rt][3], 0.f) * w3v.w;
    }
  }

  // ---- layer-3 reduce + local-ensemble combine (area via same-wave shfl) ----
  const float b3s = b3[0];
#pragma unroll
  for (int rt = 0; rt < 2; rt++) {
    float pred = s[rt];
    pred += __shfl_xor(pred, 16, 64);
    pred += __shfl_xor(pred, 32, 64);
    pred += b3s;
    float other = __shfl_xor(pred, 1, 64);   // (pass0, pass1) at adjacent l15
    float a0 = __shfl(area, rt * 16 + l15, 64);       // rows live in lanes 0-31
    float a1 = __shfl(area, rt * 16 + l15 + 1, 64);
    if (q4 == 0 && (l15 & 1) == 0) {
      int row0 = rbase + rt * 16 + l15;
      float tot = a0 + a1;
      // local_ensemble swap: pred(vx=-2)*a1/tot + pred(vx=0)*a0/tot
      out[(bid * 256 + row0) >> 1] = pred * (a1 / tot) + other * (a0 / tot);
    }
  }
}

extern "C" void kernel_launch(void* const* d_in, const int* in_sizes, int n_in,
                              void* d_out, int out_size, void* d_ws, size_t ws_size,
                              hipStream_t stream) {
  const float* coord  = (const float*)d_in[0];
  const float* latent = (const float*)d_in[1];
  const float* W1 = (const float*)d_in[2];
  const float* b1 = (const float*)d_in[3];
  const float* W2 = (const float*)d_in[4];
  const float* b2 = (const float*)d_in[5];
  const float* W3 = (const float*)d_in[6];
  const float* b3 = (const float*)d_in[7];
  float* out = (float*)d_out;
  unsigned short* wsW = (unsigned short*)d_ws;   // W1f | W2f | latbf

  prep_kernel<<<608, 256, 0, stream>>>(W1, b1, W2, latent, wsW);
  lisagon_main<<<2048, 512, 0, stream>>>(coord, wsW + 24576, wsW, wsW + 8192,
                                         b2, W3, b3, out);
}

// Round 7
// 95.749 us; speedup vs baseline: 1.4666x; 1.0181x over previous
//
#include <hip/hip_runtime.h>
#include <hip/hip_bf16.h>

typedef short s8v __attribute__((ext_vector_type(8)));      // 8 bf16 (4 VGPRs) MFMA A/B frag
typedef float f4v __attribute__((ext_vector_type(4)));      // MFMA C/D frag
typedef unsigned u4v __attribute__((ext_vector_type(4)));   // 4 packed bf16-pairs

__device__ __forceinline__ unsigned short f2bf(float x) {  // RTNE fp32->bf16 (prep only)
  unsigned u = __builtin_bit_cast(unsigned, x);
  u += 0x7fffu + ((u >> 16) & 1u);
  return (unsigned short)(u >> 16);
}
// pack 2 fp32 -> packed bf16 pair {lo=a, hi=b}
#if __has_builtin(__builtin_amdgcn_cvt_pk_bf16_f32)
__device__ __forceinline__ unsigned pk2(float a, float b) {
  return __builtin_bit_cast(unsigned, __builtin_amdgcn_cvt_pk_bf16_f32(a, b));
}
#else
__device__ __forceinline__ unsigned pk2(float a, float b) {  // 3 VALU ops, round-away
  unsigned ua = __builtin_bit_cast(unsigned, a) + 0x8000u;
  unsigned ub = __builtin_bit_cast(unsigned, b) + 0x8000u;
  return __builtin_amdgcn_perm(ub, ua, 0x07060302u);  // {ub.hi16, ua.hi16}
}
#endif

// async global->LDS DMA, 16 B per lane; LDS dest = wave-uniform base + lane*16
__device__ __forceinline__ void g2lds16(const void* g, void* l) {
  __builtin_amdgcn_global_load_lds(
      (const __attribute__((address_space(1))) unsigned*)g,
      (__attribute__((address_space(3))) unsigned*)l, 16, 0, 0);
}

// ---------------- prep: W1f/W2f fragment packs + latent->bf16 table ----------------
// ws layout (unsigned short): [0,8192) W1f, [8192,24576) W2f, [24576,+524288) latbf.
// (unchanged from R16 baseline)
__global__ void prep_kernel(const float* __restrict__ W1, const float* __restrict__ b1,
                            const float* __restrict__ W2, const float* __restrict__ latent,
                            unsigned short* __restrict__ wsW) {
  int e = blockIdx.x * 256 + threadIdx.x;   // 608*256 = 155648 = 24576 + 131072
  if (e < 8192) {
    int frag = e >> 9, rem = e & 511, lane = rem >> 3, j = rem & 7;
    int h = frag >> 1, ks = frag & 1;
    int q4 = lane >> 4, l15 = lane & 15;
    int k = ks * 32 + q4 * 8 + j;
    int n = h * 16 + l15;
    float v;
    if (k < 13) v = W1[k * 128 + n];
    else if (k == 13) v = b1[n];
    else if (k < 16) v = 0.0f;
    else v = W1[(k - 3) * 128 + n];
    wsW[e] = f2bf(v);
  } else if (e < 24576) {
    int e2 = e - 8192;
    int frag = e2 >> 9, rem = e2 & 511, lane = rem >> 3, j = rem & 7;
    int h2 = frag >> 2, ks = frag & 3;
    int q4 = lane >> 4, l15 = lane & 15;
    int kd = (j < 4) ? (32 * ks + 4 * q4 + j) : (32 * ks + 16 + 4 * q4 + (j - 4));
    int n = h2 * 16 + l15;
    wsW[e] = f2bf(W2[kd * 128 + n]);
  } else {
    int i = e - 24576;                      // 4 floats -> 2 dwords, coalesced
    float4 v = ((const float4*)latent)[i];
    uint2 o;
    o.x = pk2(v.x, v.y);
    o.y = pk2(v.z, v.w);
    ((uint2*)(wsW + 24576))[i] = o;
  }
}

// ---------------- main fused kernel (R22: early barrier, convoy-free body) ---------
// R17/R20/R21 POST-MORTEM: occupancy reshaping is a dead lever (three neutral
// results; gfx950 hidden acc allocation shadows the arch VGPR count -- R19's
// 132-VGPR kernel ran at ~1 wave/SIMD). R22 attacks the WG-internal convoy
// instead: R16's barrier sat AFTER GEMM1, so every wave waited on the slowest
// wave's phase0+gather+GEMM1 chain plus a vmcnt(0) drain of in-flight gathers.
// Moving the barrier to the TOP (right after DMA issue + BW staging, while waves
// are still lockstep and only the 32KB L2-resident DMA is outstanding) makes the
// entire body -- phase-0, gathers, GEMM1, GEMM2, epilogue -- barrier-free; waves
// slide independently. Also: dummy g0 gathers on q4<2 lanes removed (exec-masked
// if/else, ~25% less gather traffic). Everything else == R16 (rt=4, W1r preload,
// (256,2), grid 2048, XCD swizzle).
__global__ __launch_bounds__(256, 2) void lisagon_main(
    const float* __restrict__ coord, const unsigned short* __restrict__ latbf,
    const unsigned short* __restrict__ W1f, const unsigned short* __restrict__ W2f,
    const float* __restrict__ b2, const float* __restrict__ W3,
    const float* __restrict__ b3, float* __restrict__ out) {
  __shared__ __align__(16) unsigned short W2s[16384];      // 32 KB W2 fragments
  __shared__ __align__(16) unsigned PE[2][256][4];         // 8 KB: 2 planes x 256 rows
  __shared__ __align__(16) float BW[256];                  // b2 [0,128) | W3 [128,256)

  const int t = threadIdx.x;
  const int lane = t & 63, wv = t >> 6;
  const int l15 = lane & 15, q4 = lane >> 4;
  // XCD-aware swizzle (bijective on [0,2048)): physical blocks i%8==j (one XCD under
  // round-robin) all land in batch j>>1. Speed-only heuristic (G16-safe).
  const int bid = ((blockIdx.x & 7) >> 1) * 512 + ((blockIdx.x >> 3) << 1) + (blockIdx.x & 1);

  // ---- issue W2f -> LDS DMA ----
#pragma unroll
  for (int it = 0; it < 8; it++) {
    int off = (it * 4 + wv) * 1024;          // bytes; wave-uniform LDS base
    g2lds16((const char*)W2f + off + lane * 16, (char*)W2s + off);
  }
  // ---- stage b2 / W3 into LDS (1 KB) ----
  if (t < 64) {
    ((float4*)BW)[t] = (t < 32) ? ((const float4*)b2)[t] : ((const float4*)W3)[t - 32];
  }

  // ---- EARLY barrier: drains only the W2s DMA (L2-resident, ~1k cyc, hidden by
  // the co-resident WG). Waves are still lockstep here, so no convoy cost. After
  // this point the kernel is barrier-free per wave. ----
  __syncthreads();

  // ---- preload all 16 W1f fragments into registers (L1/L2-hot) ----
  const s8v* W1fv = (const s8v*)W1f;
  s8v W1r[16];
#pragma unroll
  for (int i = 0; i < 16; i++) W1r[i] = W1fv[i * 64 + lane];

  // ---- phase 0 (lite): idx + area + PE for row t; NO latent traffic ----
  int idx;
  float area;
  {
    const int Rg = bid * 256 + t;
    const int gq = Rg >> 1, p = Rg & 1;       // p=0 -> vx=-2 pass, p=1 -> vx=0 pass
    const float co = coord[gq];
    float c = (co + (p ? 0.0f : -0.000244140625f)) + 1e-6f;  // vx*rx exact
    c = fminf(fmaxf(c, -1.0f + 1e-6f), 1.0f - 1e-6f);
    double u = ((double)c * 8192.0 + 8191.0) * 0.5;          // exact searchsorted
    idx = (int)ceil(u);
    idx = min(max(idx, 0), 8191);
    float qc = ((float)(2 * idx + 1) - 8192.0f) * (1.0f / 8192.0f);  // exact grid[idx]
    float rel = (co - qc) * 8192.0f;
    area = fabsf(rel) + 1e-9f;
    float v[16];
    v[0] = rel;
    float f = rel;
#pragma unroll
    for (int i = 0; i < 6; i++) {
      v[1 + 2 * i] = __sinf(f);
      v[2 + 2 * i] = __cosf(f);
      f = f + f;                 // exact power-of-2 freqs
    }
    v[13] = 1.0f;                // bias-fold slot (W1f input dim 13 = b1)
    v[14] = 0.0f; v[15] = 0.0f;
    uint4 q0, q1;
    q0.x = pk2(v[0], v[1]);   q0.y = pk2(v[2], v[3]);
    q0.z = pk2(v[4], v[5]);   q0.w = pk2(v[6], v[7]);
    q1.x = pk2(v[8], v[9]);   q1.y = pk2(v[10], v[11]);
    q1.z = pk2(v[12], v[13]); q1.w = pk2(v[14], v[15]);
    ((uint4*)PE[0])[t] = q0;   // plane 0: values 0..7 of row t
    ((uint4*)PE[1])[t] = q1;   // plane 1: values 8..15
  }

  // ---- per-lane direct B-fragment assembly (intra-wave only; NO barrier) ----
  // chunk map: ks0: q4<2 -> PE plane q4 (LDS); q4>=2 -> prev, chunk q4&1 (global).
  // ks1: q4<2 -> self, chunk q4&1; q4>=2 -> next, chunk q4&1. Exec-masked if/else
  // so q4<2 lanes never issue the prev-row gather (R16 loaded it as a dummy).
  const size_t bbase = (size_t)(bid >> 9) * (8192 * 16);   // batch, WG-uniform
  const uint4* latv4 = (const uint4*)(latbf + bbase);   // row r chunk c = latv4[r*2+c]
  const int rbase = wv * 64;
  s8v Bf[2][4];
#pragma unroll
  for (int rt = 0; rt < 4; rt++) {
    int srcl = rt * 16 + l15;                // source lane (same wave) for this row
    int sidx = __shfl(idx, srcl, 64);
    int rp = max(sidx - 1, 0), rn = min(sidx + 1, 8191);
    int c = q4 & 1;
    uint4 g1 = latv4[(q4 < 2 ? sidx : rn) * 2 + c];      // ks1 chunk (all lanes)
    uint4 b0;
    if (q4 < 2) {
      b0 = ((const uint4*)PE[c])[rbase + srcl];          // PE chunk (LDS, same-wave)
    } else {
      b0 = latv4[rp * 2 + c];                            // prev-row chunk (global)
    }
    Bf[0][rt] = __builtin_bit_cast(s8v, b0);
    Bf[1][rt] = __builtin_bit_cast(s8v, g1);
  }

  // ---- GEMM1' (h-outer): one h-tile acc live; relu+pack DIRECTLY into bbv lanes ----
  // bbv[rt][ks] is GEMM2's B-fragment for K-chunk ks (K-permuted to match W2f):
  //   lane 2h'+half holds packed pair from GEMM1 output h = 2ks+h', half in {0,1}.
  u4v bbv[4][4];
#pragma unroll
  for (int h = 0; h < 8; h++) {
    f4v a[4];
#pragma unroll
    for (int rt = 0; rt < 4; rt++) a[rt] = (f4v){0.f, 0.f, 0.f, 0.f};
#pragma unroll
    for (int ks = 0; ks < 2; ks++) {
#pragma unroll
      for (int rt = 0; rt < 4; rt++)
        a[rt] = __builtin_amdgcn_mfma_f32_16x16x32_bf16(W1r[h * 2 + ks], Bf[ks][rt],
                                                        a[rt], 0, 0, 0);
    }
#pragma unroll
    for (int rt = 0; rt < 4; rt++) {
      bbv[rt][h >> 1][2 * (h & 1)]     = pk2(fmaxf(a[rt][0], 0.f), fmaxf(a[rt][1], 0.f));
      bbv[rt][h >> 1][2 * (h & 1) + 1] = pk2(fmaxf(a[rt][2], 0.f), fmaxf(a[rt][3], 0.f));
    }
  }

  // ---- GEMM2' (h2-outer, weights from LDS; NO barrier needed -- W2s valid since
  // the early barrier): b2 as acc-init; consume into dot ----
  const s8v* W2sv = (const s8v*)W2s;
  float s[4] = {0.f, 0.f, 0.f, 0.f};
#pragma unroll
  for (int h2 = 0; h2 < 8; h2++) {
    f4v a2[4];
    f4v b2v = ((const f4v*)BW)[h2 * 4 + q4];   // LDS broadcast; elem i -> h2 16h2+4q4+i
#pragma unroll
    for (int rt = 0; rt < 4; rt++) a2[rt] = b2v;
#pragma unroll
    for (int ks = 0; ks < 4; ks++) {
      s8v Af = W2sv[(h2 * 4 + ks) * 64 + lane];   // ds_read_b128, conflict-free
#pragma unroll
      for (int rt = 0; rt < 4; rt++)
        a2[rt] = __builtin_amdgcn_mfma_f32_16x16x32_bf16(
            Af, __builtin_bit_cast(s8v, bbv[rt][ks]), a2[rt], 0, 0, 0);
    }
    float4 w3v = ((const float4*)(BW + 128))[h2 * 4 + q4];   // LDS broadcast
#pragma unroll
    for (int rt = 0; rt < 4; rt++) {
      s[rt] += fmaxf(a2[rt][0], 0.f) * w3v.x;
      s[rt] += fmaxf(a2[rt][1], 0.f) * w3v.y;
      s[rt] += fmaxf(a2[rt][2], 0.f) * w3v.z;
      s[rt] += fmaxf(a2[rt][3], 0.f) * w3v.w;
    }
  }

  // ---- layer-3 reduce + local-ensemble combine (area via same-wave shfl) ----
  const float b3s = b3[0];
#pragma unroll
  for (int rt = 0; rt < 4; rt++) {
    float pred = s[rt];
    pred += __shfl_xor(pred, 16, 64);
    pred += __shfl_xor(pred, 32, 64);
    pred += b3s;
    float other = __shfl_xor(pred, 1, 64);   // (pass0, pass1) at adjacent l15
    float a0 = __shfl(area, rt * 16 + l15, 64);       // rows live in this wave
    float a1 = __shfl(area, rt * 16 + l15 + 1, 64);
    if (q4 == 0 && (l15 & 1) == 0) {
      int row0 = rbase + rt * 16 + l15;
      float tot = a0 + a1;
      // local_ensemble swap: pred(vx=-2)*a1/tot + pred(vx=0)*a0/tot
      out[(bid * 256 + row0) >> 1] = pred * (a1 / tot) + other * (a0 / tot);
    }
  }
}

extern "C" void kernel_launch(void* const* d_in, const int* in_sizes, int n_in,
                              void* d_out, int out_size, void* d_ws, size_t ws_size,
                              hipStream_t stream) {
  const float* coord  = (const float*)d_in[0];
  const float* latent = (const float*)d_in[1];
  const float* W1 = (const float*)d_in[2];
  const float* b1 = (const float*)d_in[3];
  const float* W2 = (const float*)d_in[4];
  const float* b2 = (const float*)d_in[5];
  const float* W3 = (const float*)d_in[6];
  const float* b3 = (const float*)d_in[7];
  float* out = (float*)d_out;
  unsigned short* wsW = (unsigned short*)d_ws;   // W1f | W2f | latbf

  prep_kernel<<<608, 256, 0, stream>>>(W1, b1, W2, latent, wsW);
  lisagon_main<<<2048, 256, 0, stream>>>(coord, wsW + 24576, wsW, wsW + 8192,
                                         b2, W3, b3, out);
}